// Round 11
// baseline (366.268 us; speedup 1.0000x reference)
//
#include <hip/hip_runtime.h>

// B=2, S=2048, HID=1024, H=16, D=64, MAX_SEQ=2048.
// Storage: fp32 holding bf16-grid values. Internal compute: bf16.

typedef __attribute__((ext_vector_type(8))) short short8;
typedef __attribute__((ext_vector_type(4))) short short4v;
typedef __attribute__((ext_vector_type(4))) float f32x4;

__device__ __forceinline__ float bf2f(unsigned short u) {
  return __uint_as_float(((unsigned int)u) << 16);
}
__device__ __forceinline__ unsigned short f2bf(float f) {
  unsigned int u = __float_as_uint(f);
  u += 0x7fffu + ((u >> 16) & 1u);   // RNE
  return (unsigned short)(u >> 16);
}

#define GLL16(gp, lp) __builtin_amdgcn_global_load_lds( \
    (const __attribute__((address_space(1))) void*)(gp), \
    (__attribute__((address_space(3))) void*)(lp), 16, 0, 0)

#define MFMA16(a, b, c)  __builtin_amdgcn_mfma_f32_16x16x32_bf16((a), (b), (c), 0, 0, 0)

// ---------------------------------------------------------------------------
// prep: fp32->bf16 converts + rope cos/sin table + rel transpose.
// ---------------------------------------------------------------------------
__global__ __launch_bounds__(256) void prep_kernel(
    const float* __restrict__ q, const float* __restrict__ k,
    const float* __restrict__ v,
    const float* __restrict__ wq, const float* __restrict__ wk,
    const float* __restrict__ wv, const float* __restrict__ wo,
    unsigned short* __restrict__ xq, unsigned short* __restrict__ xk,
    unsigned short* __restrict__ xv,
    unsigned short* __restrict__ wqb, unsigned short* __restrict__ wkb,
    unsigned short* __restrict__ wvb, unsigned short* __restrict__ wob,
    float* __restrict__ tab, float* __restrict__ relt,
    const float* __restrict__ rel)
{
  int tid = blockIdx.x * 256 + threadIdx.x;
  if (tid < 2097152) {          // converts
    const float* src; unsigned short* dst; size_t off;
    if (tid < 1572864) {
      int seg = tid / 524288, rc = tid - seg * 524288;
      src = seg == 0 ? q : (seg == 1 ? k : v);
      dst = seg == 0 ? xq : (seg == 1 ? xk : xv);
      off = (size_t)rc * 8;
    } else {
      int c2 = tid - 1572864;
      int seg = c2 / 131072, rc = c2 - seg * 131072;
      src = seg == 0 ? wq : (seg == 1 ? wk : (seg == 2 ? wv : wo));
      dst = seg == 0 ? wqb : (seg == 1 ? wkb : (seg == 2 ? wvb : wob));
      off = (size_t)rc * 8;
    }
    float4 f0 = ((const float4*)(src + off))[0];
    float4 f1 = ((const float4*)(src + off))[1];
    short8 o;
    o[0]=f2bf(f0.x); o[1]=f2bf(f0.y); o[2]=f2bf(f0.z); o[3]=f2bf(f0.w);
    o[4]=f2bf(f1.x); o[5]=f2bf(f1.y); o[6]=f2bf(f1.z); o[7]=f2bf(f1.w);
    *(short8*)(dst + off) = o;
  } else if (tid < 2162688) {   // rope table
    int u = tid - 2097152;
    int s = u >> 5, j = u & 31;
    float f = expf((float)j * -0.28782313662425575f);   // 10000^(-j/32)
    float sn, cs;
    sincosf((float)s * f, &sn, &cs);
    tab[s * 64 + j] = cs;
    tab[s * 64 + 32 + j] = sn;
  } else {                      // relt[h][d] = rel[d][h]
    int u = tid - 2162688;
    int hh = u >> 12, d = u & 4095;
    if (d < 4095) relt[hh * 4095 + d] = rel[d * 16 + hh];
  }
}

// ---------------------------------------------------------------------------
// Fused QKV GEMM, m97 structure: 128x128 tile, BK=32, 16 MFMA/iter, GLL16.
// N=3072 (Wcat = Wq|Wk|Wv contiguous); z = n0>>10 selects X/bias/output.
// z<2 (Q,K): swapped mfma -> r along n(=d) -> short4 scatter [B,H,S,D].
// z==2 (V): unswapped -> r along m(=s) -> short4 scatter [B,H,D,S].
// Grid 24 x 32 = 768 blocks.
// ---------------------------------------------------------------------------
template<bool SWAP>
__device__ __forceinline__ void core128x128(
    const unsigned short* gA, const unsigned short* gB,
    unsigned short* As, unsigned short* Bs,
    f32x4 (&acc)[4][4], int t, int wm, int wn, int lid, int quad)
{
  for (int k0 = 0; k0 < 1024; k0 += 32) {
    __syncthreads();
    GLL16(gA + k0,         As + t * 8);
    GLL16(gA + 65536 + k0, As + 2048 + t * 8);   // rows 64..127
    GLL16(gB + k0,         Bs + t * 8);
    GLL16(gB + 65536 + k0, Bs + 2048 + t * 8);
    __syncthreads();
    short8 af[4], bf[4];
#pragma unroll
    for (int i = 0; i < 4; i++)
      af[i] = *(const short8*)(As + (wm + i * 16 + lid) * 32 + quad * 8);
#pragma unroll
    for (int j = 0; j < 4; j++)
      bf[j] = *(const short8*)(Bs + (wn + j * 16 + lid) * 32 + quad * 8);
#pragma unroll
    for (int i = 0; i < 4; i++)
#pragma unroll
      for (int j = 0; j < 4; j++)
        acc[i][j] = SWAP ? MFMA16(bf[j], af[i], acc[i][j])
                         : MFMA16(af[i], bf[j], acc[i][j]);
  }
}

__global__ __launch_bounds__(256) void gemm_qkv(
    const unsigned short* __restrict__ Xq, const unsigned short* __restrict__ Xk,
    const unsigned short* __restrict__ Xv,
    const unsigned short* __restrict__ Wcat,
    const float* __restrict__ bq, const float* __restrict__ bk,
    const float* __restrict__ bv,
    unsigned short* __restrict__ Qr, unsigned short* __restrict__ Kr,
    unsigned short* __restrict__ Vtr)
{
  __shared__ unsigned short As[128 * 32];
  __shared__ unsigned short Bs[128 * 32];

  const int t    = threadIdx.x;
  const int lane = t & 63;
  const int lid  = lane & 15;
  const int quad = lane >> 4;
  const int w    = t >> 6;
  const int wm   = (w >> 1) * 64;
  const int wn   = (w & 1) * 64;
  const int n0   = blockIdx.x * 128;
  const int m0   = blockIdx.y * 128;
  const int z    = n0 >> 10;                      // 0=Q 1=K 2=V

  const unsigned short* X = z == 0 ? Xq : (z == 1 ? Xk : Xv);
  const float* Bi = z == 0 ? bq : (z == 1 ? bk : bv);

  const unsigned short* gA = X    + (size_t)(m0 + (t >> 2)) * 1024 + (t & 3) * 8;
  const unsigned short* gB = Wcat + (size_t)(n0 + (t >> 2)) * 1024 + (t & 3) * 8;

  f32x4 acc[4][4];
#pragma unroll
  for (int i = 0; i < 4; i++)
#pragma unroll
    for (int j = 0; j < 4; j++) acc[i][j] = (f32x4){0.f, 0.f, 0.f, 0.f};

  if (z == 2) core128x128<false>(gA, gB, As, Bs, acc, t, wm, wn, lid, quad);
  else        core128x128<true >(gA, gB, As, Bs, acc, t, wm, wn, lid, quad);

  if (z < 2) {   // swapped: D row(quad*4+r)=n(d), col(lid)=m(s); short4 along d
    unsigned short* O = z == 0 ? Qr : Kr;
#pragma unroll
    for (int jn = 0; jn < 4; jn++) {
      int nn = n0 + wn + jn * 16 + quad * 4;      // absolute col in [z*1024 ..)
      int nc = nn & 1023;
      int hh = nc >> 6, d0 = nc & 63;
      float4 b4 = *(const float4*)(Bi + nc);
#pragma unroll
      for (int im = 0; im < 4; im++) {
        int m = m0 + wm + im * 16 + lid;
        int bb = m >> 11, s = m & 2047;
        short4v pk;
        pk[0] = (short)f2bf(acc[im][jn][0] + b4.x);
        pk[1] = (short)f2bf(acc[im][jn][1] + b4.y);
        pk[2] = (short)f2bf(acc[im][jn][2] + b4.z);
        pk[3] = (short)f2bf(acc[im][jn][3] + b4.w);
        *(short4v*)(O + ((size_t)((bb * 16 + hh) * 2048 + s)) * 64 + d0) = pk;
      }
    }
  } else {       // unswapped: row=m(s), col=n(d); short4 along s into [B,H,D,S]
#pragma unroll
    for (int j = 0; j < 4; j++) {
      int n = n0 + wn + j * 16 + lid;
      int nc = n & 1023;
      int hh = nc >> 6, d = nc & 63;
      float bvv = Bi[nc];
#pragma unroll
      for (int i = 0; i < 4; i++) {
        int mr = m0 + wm + i * 16 + quad * 4;
        int bb = mr >> 11, s0 = mr & 2047;
        short4v pk;
        pk[0] = (short)f2bf(acc[i][j][0] + bvv);
        pk[1] = (short)f2bf(acc[i][j][1] + bvv);
        pk[2] = (short)f2bf(acc[i][j][2] + bvv);
        pk[3] = (short)f2bf(acc[i][j][3] + bvv);
        *(short4v*)(Vtr + ((size_t)((bb * 16 + hh) * 64 + d)) * 2048 + s0) = pk;
      }
    }
  }
}

// ---------------------------------------------------------------------------
// Output projection: 128x64 tile, BK=64 (16 MFMA + 6 GLL16 per barrier-pair),
// 24 KB LDS, grid 16 x 32 = 512 blocks. fp32 float4 output.
// ---------------------------------------------------------------------------
__global__ __launch_bounds__(256) void gemm_out(
    const unsigned short* __restrict__ X, const unsigned short* __restrict__ W,
    const float* __restrict__ Bi, float* __restrict__ O)
{
  __shared__ unsigned short As[128 * 64];   // 16 KB
  __shared__ unsigned short Bs[64 * 64];    // 8 KB
  const int t    = threadIdx.x;
  const int lane = t & 63;
  const int lid  = lane & 15;
  const int quad = lane >> 4;
  const int w    = t >> 6;
  const int wm   = (w >> 1) * 64;
  const int wn   = (w & 1) * 32;
  const int m0   = blockIdx.y * 128;
  const int n0   = blockIdx.x * 64;

  // chunk c (16B): row = c>>3, kk = (c&7)*8
  const unsigned short* gA = X + (size_t)(m0 + (t >> 3)) * 1024 + (t & 7) * 8;
  const unsigned short* gB = W + (size_t)(n0 + (t >> 3)) * 1024 + (t & 7) * 8;

  f32x4 acc[4][2];
#pragma unroll
  for (int i = 0; i < 4; i++)
#pragma unroll
    for (int j = 0; j < 2; j++) acc[i][j] = (f32x4){0.f, 0.f, 0.f, 0.f};

  for (int k0 = 0; k0 < 1024; k0 += 64) {
    __syncthreads();
#pragma unroll
    for (int i = 0; i < 4; i++)                     // A: 128 rows x 64 k
      GLL16(gA + (size_t)(i * 32) * 1024 + k0, As + (i * 256 + t) * 8);
#pragma unroll
    for (int i = 0; i < 2; i++)                     // B: 64 rows x 64 k
      GLL16(gB + (size_t)(i * 32) * 1024 + k0, Bs + (i * 256 + t) * 8);
    __syncthreads();
#pragma unroll
    for (int ks = 0; ks < 2; ks++) {
      short8 af[4], bf[2];
#pragma unroll
      for (int i = 0; i < 4; i++)
        af[i] = *(const short8*)(As + (wm + i * 16 + lid) * 64 + ks * 32 + quad * 8);
#pragma unroll
      for (int j = 0; j < 2; j++)
        bf[j] = *(const short8*)(Bs + (wn + j * 16 + lid) * 64 + ks * 32 + quad * 8);
#pragma unroll
      for (int i = 0; i < 4; i++)
#pragma unroll
        for (int j = 0; j < 2; j++)
          acc[i][j] = MFMA16(bf[j], af[i], acc[i][j]);   // swapped
    }
  }
#pragma unroll
  for (int jn = 0; jn < 2; jn++) {
    int nn = n0 + wn + jn * 16 + quad * 4;
    float4 b4 = *(const float4*)(Bi + nn);
#pragma unroll
    for (int im = 0; im < 4; im++) {
      int m = m0 + wm + im * 16 + lid;
      float4 ov;
      ov.x = acc[im][jn][0] + b4.x;
      ov.y = acc[im][jn][1] + b4.y;
      ov.z = acc[im][jn][2] + b4.z;
      ov.w = acc[im][jn][3] + b4.w;
      *(float4*)(O + (size_t)m * 1024 + nn) = ov;
    }
  }
}

// ---------------------------------------------------------------------------
// RoPE apply (reference variant), in-place on bf16 [B,H,S,64].
// ---------------------------------------------------------------------------
__global__ __launch_bounds__(256) void rope_kernel(unsigned short* __restrict__ Q,
                                                   unsigned short* __restrict__ Kp,
                                                   const float* __restrict__ tab)
{
  int row = blockIdx.x * 256 + threadIdx.x;
  unsigned short* P = ((blockIdx.y == 0) ? Q : Kp) + (size_t)row * 64;
  const float* tr = tab + (size_t)(row & 2047) * 64;

  short8 xv[8];
#pragma unroll
  for (int c = 0; c < 8; c++) xv[c] = *(const short8*)(P + c * 8);
#define XE(i) bf2f((unsigned short)xv[(i) >> 3][(i) & 7])
  short8 ov[8];
#pragma unroll
  for (int j = 0; j < 32; j++) {
    float cs = tr[j], sn = tr[32 + j];
    float yl = XE(j) * cs      - XE(2 * j + 1) * sn;
    float yh = XE(j + 32) * cs + XE(2 * j)     * sn;
    ov[j >> 3][j & 7]       = (short)f2bf(yl);
    ov[(j >> 3) + 4][j & 7] = (short)f2bf(yh);
  }
#undef XE
#pragma unroll
  for (int c = 0; c < 8; c++) *(short8*)(P + c * 8) = ov[c];
}

// ---------------------------------------------------------------------------
// Flash attention, 4 strips/block (2 heavy + 2 light), k-split=2, XCD swizzle.
// R9 post-mortem: per-proc cost ~7000 cyc >> ~400-cyc chain model -> bound by
// MEMORY-REQUEST RATE: each K/V fragment load is 16-segment strided (lid
// strides 128 B in K, 4 KB in V); ~256 requests/proc through the CU's shared
// L1/addr path; ~1 GB L2 reads for 33 MB unique. Fix: merge two strip-pairs
// per block so each loaded K/V tile feeds 4 strips (64 q-rows) -> HALF the
// requests per unit work. Work stays balanced (66 procs/block for all P).
// Grid 1024 = exactly 4 blocks/CU x 2 waves -> single full-residency pass.
// proc is byte-identical to R6 (proven). Loop = R6 (cv same-iter, ck/nk
// prefetch). Regs ~230 incl acc < 256 cap of (128,2) -> no spill (tripwire:
// WRITE_SIZE 8.2 MB). Ps aliases the combine buffer; extra barrier protects.
// ---------------------------------------------------------------------------
__global__ __launch_bounds__(128, 2) void attn_kernel(
    const unsigned short* __restrict__ Q, const unsigned short* __restrict__ Kg,
    const unsigned short* __restrict__ Vt, const float* __restrict__ relt,
    unsigned short* __restrict__ AO)
{
  __shared__ float Smem[5120];   // 20.5 KB: Ps (2x9216B) ∪ Cmb (20480B)

  const int tid  = threadIdx.x;
  const int wv   = tid >> 6;            // wave id 0/1
  const int lane = tid & 63;
  const int lid  = lane & 15;
  const int quad = lane >> 4;
  const int x    = blockIdx.x;          // 0..1023
  const int bh   = (x & 7) * 4 + (x >> 8);   // XCD-locality: same bh -> same xcd
  const int P    = (x >> 3) & 31;
  const int h    = bh & 15;

  // 4 strips: heavy pair (q0,q1) + light pair (q2,q3); per-pair sums constant.
  const int q0 = 2032 - 32 * P;
  const int q1 = 2016 - 32 * P;
  const int q2 = 32 * P;
  const int q3 = 32 * P + 16;
  const int kend0 = q0 + 16;            // loop bound (max of all strips)
  const int kend2 = q2 + 16, kend3 = q3 + 16;

  const unsigned short* Qb = Q  + (size_t)bh * (2048 * 64);
  const unsigned short* Kb = Kg + (size_t)bh * (2048 * 64);
  const unsigned short* Vb = Vt + (size_t)bh * (64 * 2048);
  const float* relh = relt + h * 4095 + 2047;
  unsigned short* AOb = AO + (size_t)(bh >> 4) * (2048 * 1024) + h * 64;

  unsigned short* Psw = (unsigned short*)Smem + wv * 4608;  // 64 rows x 72

  const int qbase[4] = {q0, q1, q2, q3};
  short8 aq[4][2];
#pragma unroll
  for (int s = 0; s < 4; s++) {
    const unsigned short* qp = Qb + (size_t)(qbase[s] + lid) * 64;
    aq[s][0] = *(const short8*)(qp + quad * 8);
    aq[s][1] = *(const short8*)(qp + 32 + quad * 8);
  }

  f32x4 acc[4][4];
  float l[4][4];
#pragma unroll
  for (int s = 0; s < 4; s++)
#pragma unroll
    for (int dj = 0; dj < 4; dj++) {
      acc[s][dj] = (f32x4){0.f, 0.f, 0.f, 0.f};
      l[s][dj] = 0.f;
    }

  const unsigned short* kr = Kb + (size_t)lid * 64 + quad * 8;
  const unsigned short* vr = Vb + (size_t)lid * 2048 + quad * 8;

  short8 ck[4][2], nk[4][2], cv[4][2];

  auto loadK = [&](short8 (&fk)[4][2], int k0) {
#pragma unroll
    for (int x2 = 0; x2 < 4; x2++) {
      const unsigned short* kp = kr + (size_t)(k0 + x2 * 16) * 64;
      fk[x2][0] = *(const short8*)kp;
      fk[x2][1] = *(const short8*)(kp + 32);
    }
  };
  auto loadV = [&](short8 (&fv)[4][2], int k0) {
#pragma unroll
    for (int x2 = 0; x2 < 4; x2++) {
      const unsigned short* vp = vr + (size_t)(x2 * 16) * 2048 + k0;
      fv[x2][0] = *(const short8*)vp;
      fv[x2][1] = *(const short8*)(vp + 32);
    }
  };
  auto proc = [&](const short8 (&a_q)[2], f32x4 (&acc_)[4], float (&l_)[4],
                  int qr0, int k0, const short8 (&fk)[4][2],
                  const short8 (&fv)[4][2], int pbase) {
    f32x4 s4[4];
#pragma unroll
    for (int jt = 0; jt < 4; jt++) {
      s4[jt] = (f32x4){0.f, 0.f, 0.f, 0.f};
      s4[jt] = MFMA16(a_q[0], fk[jt][0], s4[jt]);
      s4[jt] = MFMA16(a_q[1], fk[jt][1], s4[jt]);
    }
#pragma unroll
    for (int jt = 0; jt < 4; jt++) {
      int kb = k0 + jt * 16 + lid;
      const float* rp = relh + (qr0 - kb);
#pragma unroll
      for (int r = 0; r < 4; r++) {
        float sc = fmaf(s4[jt][r], 0.125f, rp[r]);
        float pv = (kb > qr0 + r) ? 0.f : __expf(sc);
        l_[r] += pv;
        Psw[(pbase + quad * 4 + r) * 72 + jt * 16 + lid] = f2bf(pv);
      }
    }
    short8 ap0 = *(const short8*)(Psw + (pbase + lid) * 72 + quad * 8);
    short8 ap1 = *(const short8*)(Psw + (pbase + lid) * 72 + 32 + quad * 8);
#pragma unroll
    for (int dj = 0; dj < 4; dj++) {
      acc_[dj] = MFMA16(ap0, fv[dj][0], acc_[dj]);
      acc_[dj] = MFMA16(ap1, fv[dj][1], acc_[dj]);
    }
  };

  const int qr0q = q0 + quad * 4, qr1q = q1 + quad * 4;
  const int qr2q = q2 + quad * 4, qr3q = q3 + quad * 4;

  auto PROCS = [&](int k0, const short8 (&fk)[4][2], const short8 (&fv)[4][2]) {
    proc(aq[0], acc[0], l[0], qr0q, k0, fk, fv, 0);
    proc(aq[1], acc[1], l[1], qr1q, k0, fk, fv, 16);
    if (k0 < kend2) proc(aq[2], acc[2], l[2], qr2q, k0, fk, fv, 32);
    if (k0 < kend3) proc(aq[3], acc[3], l[3], qr3q, k0, fk, fv, 48);
  };

  int k0 = wv * 64;               // interleaved k-split: parity of (k0/64)
  if (k0 < kend0) {
    loadK(ck, k0);
    while (true) {
      int k1 = k0 + 128;
      if (k1 < kend0) loadK(nk, k1);
      loadV(cv, k0);
      PROCS(k0, ck, cv);
      if (k1 >= kend0) break;
      k0 = k1; k1 = k0 + 128;
      if (k1 < kend0) loadK(ck, k1);
      loadV(cv, k0);
      PROCS(k0, nk, cv);
      if (k1 >= kend0) break;
      k0 = k1;
    }
  }

  // reduce l across the 16 lanes of each quad (within wave)
#pragma unroll
  for (int d2 = 1; d2 < 16; d2 <<= 1)
#pragma unroll
    for (int s = 0; s < 4; s++)
#pragma unroll
      for (int r = 0; r < 4; r++)
        l[s][r] += __shfl_xor(l[s][r], d2);

  // Ps is dead from here; Cmb aliases it -> barrier before overwrite.
  __syncthreads();
  if (wv == 1) {
    float* C = Smem + lane * 80;
#pragma unroll
    for (int s = 0; s < 4; s++) {
#pragma unroll
      for (int dj = 0; dj < 4; dj++)
#pragma unroll
        for (int r = 0; r < 4; r++)
          C[s * 20 + dj * 4 + r] = acc[s][dj][r];
#pragma unroll
      for (int r = 0; r < 4; r++)
        C[s * 20 + 16 + r] = l[s][r];
    }
  }
  __syncthreads();
  if (wv == 0) {
    const float* C = Smem + lane * 80;
#pragma unroll
    for (int s = 0; s < 4; s++) {
#pragma unroll
      for (int dj = 0; dj < 4; dj++)
#pragma unroll
        for (int r = 0; r < 4; r++)
          acc[s][dj][r] += C[s * 20 + dj * 4 + r];
#pragma unroll
      for (int r = 0; r < 4; r++)
        l[s][r] += C[s * 20 + 16 + r];
    }
    const int qrq[4] = {qr0q, qr1q, qr2q, qr3q};
#pragma unroll
    for (int s = 0; s < 4; s++)
#pragma unroll
      for (int r = 0; r < 4; r++) {
        float rl = 1.f / l[s][r];
#pragma unroll
        for (int dj = 0; dj < 4; dj++) {
          float vv = fminf(fmaxf(acc[s][dj][r] * rl, -30.f), 30.f);
          AOb[(size_t)(qrq[s] + r) * 1024 + dj * 16 + lid] = f2bf(vv);
        }
      }
  }
}

// ---------------------------------------------------------------------------
extern "C" void kernel_launch(void* const* d_in, const int* in_sizes, int n_in,
                              void* d_out, int out_size, void* d_ws, size_t ws_size,
                              hipStream_t stream) {
  const float* query  = (const float*)d_in[0];
  const float* key_in = (const float*)d_in[1];
  const float* value  = (const float*)d_in[2];
  const float* wq = (const float*)d_in[4];
  const float* bq = (const float*)d_in[5];
  const float* wk = (const float*)d_in[6];
  const float* bk = (const float*)d_in[7];
  const float* wv = (const float*)d_in[8];
  const float* bv = (const float*)d_in[9];
  const float* wo = (const float*)d_in[10];
  const float* bo = (const float*)d_in[11];
  const float* rel = (const float*)d_in[12];

  char* ws = (char*)d_ws;
  unsigned short* Xq = (unsigned short*)(ws);                 // 8.39 MB
  unsigned short* Xk = (unsigned short*)(ws + 8388608);
  unsigned short* Xv = (unsigned short*)(ws + 16777216);
  unsigned short* Wq = (unsigned short*)(ws + 25165824);      // Wq|Wk|Wv|Wo
  unsigned short* Wk = (unsigned short*)(ws + 27262976);      //  contiguous
  unsigned short* Wv = (unsigned short*)(ws + 29360128);      //  -> Wcat
  unsigned short* Wo = (unsigned short*)(ws + 31457280);
  unsigned short* Qr  = (unsigned short*)(ws + 33554432);     // 8.39 MB
  unsigned short* Kr  = (unsigned short*)(ws + 41943040);
  unsigned short* Vtr = (unsigned short*)(ws + 50331648);     // [B,H,D,S]
  unsigned short* AOp = Xq;            // alias: Xq dead after gemm_qkv
  // tab/relt live in d_out scratch (overwritten by gemm_out at the end)
  float* out  = (float*)d_out;
  float* tab  = out;                   // 131072 floats
  float* relt = out + 131072;          // 65520 floats

  dim3 blk(256);
  prep_kernel<<<dim3(8704), blk, 0, stream>>>(
      query, key_in, value, wq, wk, wv, wo,
      Xq, Xk, Xv, Wq, Wk, Wv, Wo, tab, relt, rel);
  gemm_qkv<<<dim3(24, 32), blk, 0, stream>>>(
      Xq, Xk, Xv, Wq /*=Wcat*/, bq, bk, bv, Qr, Kr, Vtr);
  rope_kernel<<<dim3(256, 2), blk, 0, stream>>>(Qr, Kr, tab);
  attn_kernel<<<dim3(1024), dim3(128), 0, stream>>>(Qr, Kr, Vtr, relt, AOp);
  gemm_out<<<dim3(16, 32), blk, 0, stream>>>(AOp, Wo, bo, out);
}

// Round 19
// 306.187 us; speedup vs baseline: 1.1962x; 1.1962x over previous
//
#include <hip/hip_runtime.h>

// B=2, S=2048, HID=1024, H=16, D=64, MAX_SEQ=2048.
// Storage: fp32 holding bf16-grid values. Internal compute: bf16.

typedef __attribute__((ext_vector_type(8))) short short8;
typedef __attribute__((ext_vector_type(4))) short short4v;
typedef __attribute__((ext_vector_type(4))) float f32x4;

__device__ __forceinline__ float bf2f(unsigned short u) {
  return __uint_as_float(((unsigned int)u) << 16);
}
__device__ __forceinline__ unsigned short f2bf(float f) {
  unsigned int u = __float_as_uint(f);
  u += 0x7fffu + ((u >> 16) & 1u);   // RNE
  return (unsigned short)(u >> 16);
}

#define GLL16(gp, lp) __builtin_amdgcn_global_load_lds( \
    (const __attribute__((address_space(1))) void*)(gp), \
    (__attribute__((address_space(3))) void*)(lp), 16, 0, 0)

#define MFMA16(a, b, c)  __builtin_amdgcn_mfma_f32_16x16x32_bf16((a), (b), (c), 0, 0, 0)

// ---------------------------------------------------------------------------
// prep: fp32->bf16 converts + rope cos/sin table + rel transpose.
// ---------------------------------------------------------------------------
__global__ __launch_bounds__(256) void prep_kernel(
    const float* __restrict__ q, const float* __restrict__ k,
    const float* __restrict__ v,
    const float* __restrict__ wq, const float* __restrict__ wk,
    const float* __restrict__ wv, const float* __restrict__ wo,
    unsigned short* __restrict__ xq, unsigned short* __restrict__ xk,
    unsigned short* __restrict__ xv,
    unsigned short* __restrict__ wqb, unsigned short* __restrict__ wkb,
    unsigned short* __restrict__ wvb, unsigned short* __restrict__ wob,
    float* __restrict__ tab, float* __restrict__ relt,
    const float* __restrict__ rel)
{
  int tid = blockIdx.x * 256 + threadIdx.x;
  if (tid < 2097152) {          // converts
    const float* src; unsigned short* dst; size_t off;
    if (tid < 1572864) {
      int seg = tid / 524288, rc = tid - seg * 524288;
      src = seg == 0 ? q : (seg == 1 ? k : v);
      dst = seg == 0 ? xq : (seg == 1 ? xk : xv);
      off = (size_t)rc * 8;
    } else {
      int c2 = tid - 1572864;
      int seg = c2 / 131072, rc = c2 - seg * 131072;
      src = seg == 0 ? wq : (seg == 1 ? wk : (seg == 2 ? wv : wo));
      dst = seg == 0 ? wqb : (seg == 1 ? wkb : (seg == 2 ? wvb : wob));
      off = (size_t)rc * 8;
    }
    float4 f0 = ((const float4*)(src + off))[0];
    float4 f1 = ((const float4*)(src + off))[1];
    short8 o;
    o[0]=f2bf(f0.x); o[1]=f2bf(f0.y); o[2]=f2bf(f0.z); o[3]=f2bf(f0.w);
    o[4]=f2bf(f1.x); o[5]=f2bf(f1.y); o[6]=f2bf(f1.z); o[7]=f2bf(f1.w);
    *(short8*)(dst + off) = o;
  } else if (tid < 2162688) {   // rope table
    int u = tid - 2097152;
    int s = u >> 5, j = u & 31;
    float f = expf((float)j * -0.28782313662425575f);   // 10000^(-j/32)
    float sn, cs;
    sincosf((float)s * f, &sn, &cs);
    tab[s * 64 + j] = cs;
    tab[s * 64 + 32 + j] = sn;
  } else {                      // relt[h][d] = rel[d][h]
    int u = tid - 2162688;
    int hh = u >> 12, d = u & 4095;
    if (d < 4095) relt[hh * 4095 + d] = rel[d * 16 + hh];
  }
}

// ---------------------------------------------------------------------------
// Fused QKV GEMM, m97 structure: 128x128 tile, BK=32, 16 MFMA/iter, GLL16.
// N=3072 (Wcat = Wq|Wk|Wv contiguous); z = n0>>10 selects X/bias/output.
// z<2 (Q,K): swapped mfma -> r along n(=d) -> short4 scatter [B,H,S,D].
// z==2 (V): unswapped -> r along m(=s) -> short4 scatter [B,H,D,S].
// Grid 24 x 32 = 768 blocks.
// ---------------------------------------------------------------------------
template<bool SWAP>
__device__ __forceinline__ void core128x128(
    const unsigned short* gA, const unsigned short* gB,
    unsigned short* As, unsigned short* Bs,
    f32x4 (&acc)[4][4], int t, int wm, int wn, int lid, int quad)
{
  for (int k0 = 0; k0 < 1024; k0 += 32) {
    __syncthreads();
    GLL16(gA + k0,         As + t * 8);
    GLL16(gA + 65536 + k0, As + 2048 + t * 8);   // rows 64..127
    GLL16(gB + k0,         Bs + t * 8);
    GLL16(gB + 65536 + k0, Bs + 2048 + t * 8);
    __syncthreads();
    short8 af[4], bf[4];
#pragma unroll
    for (int i = 0; i < 4; i++)
      af[i] = *(const short8*)(As + (wm + i * 16 + lid) * 32 + quad * 8);
#pragma unroll
    for (int j = 0; j < 4; j++)
      bf[j] = *(const short8*)(Bs + (wn + j * 16 + lid) * 32 + quad * 8);
#pragma unroll
    for (int i = 0; i < 4; i++)
#pragma unroll
      for (int j = 0; j < 4; j++)
        acc[i][j] = SWAP ? MFMA16(bf[j], af[i], acc[i][j])
                         : MFMA16(af[i], bf[j], acc[i][j]);
  }
}

__global__ __launch_bounds__(256) void gemm_qkv(
    const unsigned short* __restrict__ Xq, const unsigned short* __restrict__ Xk,
    const unsigned short* __restrict__ Xv,
    const unsigned short* __restrict__ Wcat,
    const float* __restrict__ bq, const float* __restrict__ bk,
    const float* __restrict__ bv,
    unsigned short* __restrict__ Qr, unsigned short* __restrict__ Kr,
    unsigned short* __restrict__ Vtr)
{
  __shared__ unsigned short As[128 * 32];
  __shared__ unsigned short Bs[128 * 32];

  const int t    = threadIdx.x;
  const int lane = t & 63;
  const int lid  = lane & 15;
  const int quad = lane >> 4;
  const int w    = t >> 6;
  const int wm   = (w >> 1) * 64;
  const int wn   = (w & 1) * 64;
  const int n0   = blockIdx.x * 128;
  const int m0   = blockIdx.y * 128;
  const int z    = n0 >> 10;                      // 0=Q 1=K 2=V

  const unsigned short* X = z == 0 ? Xq : (z == 1 ? Xk : Xv);
  const float* Bi = z == 0 ? bq : (z == 1 ? bk : bv);

  const unsigned short* gA = X    + (size_t)(m0 + (t >> 2)) * 1024 + (t & 3) * 8;
  const unsigned short* gB = Wcat + (size_t)(n0 + (t >> 2)) * 1024 + (t & 3) * 8;

  f32x4 acc[4][4];
#pragma unroll
  for (int i = 0; i < 4; i++)
#pragma unroll
    for (int j = 0; j < 4; j++) acc[i][j] = (f32x4){0.f, 0.f, 0.f, 0.f};

  if (z == 2) core128x128<false>(gA, gB, As, Bs, acc, t, wm, wn, lid, quad);
  else        core128x128<true >(gA, gB, As, Bs, acc, t, wm, wn, lid, quad);

  if (z < 2) {   // swapped: D row(quad*4+r)=n(d), col(lid)=m(s); short4 along d
    unsigned short* O = z == 0 ? Qr : Kr;
#pragma unroll
    for (int jn = 0; jn < 4; jn++) {
      int nn = n0 + wn + jn * 16 + quad * 4;      // absolute col in [z*1024 ..)
      int nc = nn & 1023;
      int hh = nc >> 6, d0 = nc & 63;
      float4 b4 = *(const float4*)(Bi + nc);
#pragma unroll
      for (int im = 0; im < 4; im++) {
        int m = m0 + wm + im * 16 + lid;
        int bb = m >> 11, s = m & 2047;
        short4v pk;
        pk[0] = (short)f2bf(acc[im][jn][0] + b4.x);
        pk[1] = (short)f2bf(acc[im][jn][1] + b4.y);
        pk[2] = (short)f2bf(acc[im][jn][2] + b4.z);
        pk[3] = (short)f2bf(acc[im][jn][3] + b4.w);
        *(short4v*)(O + ((size_t)((bb * 16 + hh) * 2048 + s)) * 64 + d0) = pk;
      }
    }
  } else {       // unswapped: row=m(s), col=n(d); short4 along s into [B,H,D,S]
#pragma unroll
    for (int j = 0; j < 4; j++) {
      int n = n0 + wn + j * 16 + lid;
      int nc = n & 1023;
      int hh = nc >> 6, d = nc & 63;
      float bvv = Bi[nc];
#pragma unroll
      for (int i = 0; i < 4; i++) {
        int mr = m0 + wm + i * 16 + quad * 4;
        int bb = mr >> 11, s0 = mr & 2047;
        short4v pk;
        pk[0] = (short)f2bf(acc[i][j][0] + bvv);
        pk[1] = (short)f2bf(acc[i][j][1] + bvv);
        pk[2] = (short)f2bf(acc[i][j][2] + bvv);
        pk[3] = (short)f2bf(acc[i][j][3] + bvv);
        *(short4v*)(Vtr + ((size_t)((bb * 16 + hh) * 64 + d)) * 2048 + s0) = pk;
      }
    }
  }
}

// ---------------------------------------------------------------------------
// Output projection: 128x64 tile, BK=64 (16 MFMA + 6 GLL16 per barrier-pair),
// 24 KB LDS, grid 16 x 32 = 512 blocks. fp32 float4 output.
// ---------------------------------------------------------------------------
__global__ __launch_bounds__(256) void gemm_out(
    const unsigned short* __restrict__ X, const unsigned short* __restrict__ W,
    const float* __restrict__ Bi, float* __restrict__ O)
{
  __shared__ unsigned short As[128 * 64];   // 16 KB
  __shared__ unsigned short Bs[64 * 64];    // 8 KB
  const int t    = threadIdx.x;
  const int lane = t & 63;
  const int lid  = lane & 15;
  const int quad = lane >> 4;
  const int w    = t >> 6;
  const int wm   = (w >> 1) * 64;
  const int wn   = (w & 1) * 32;
  const int m0   = blockIdx.y * 128;
  const int n0   = blockIdx.x * 64;

  // chunk c (16B): row = c>>3, kk = (c&7)*8
  const unsigned short* gA = X + (size_t)(m0 + (t >> 3)) * 1024 + (t & 7) * 8;
  const unsigned short* gB = W + (size_t)(n0 + (t >> 3)) * 1024 + (t & 7) * 8;

  f32x4 acc[4][2];
#pragma unroll
  for (int i = 0; i < 4; i++)
#pragma unroll
    for (int j = 0; j < 2; j++) acc[i][j] = (f32x4){0.f, 0.f, 0.f, 0.f};

  for (int k0 = 0; k0 < 1024; k0 += 64) {
    __syncthreads();
#pragma unroll
    for (int i = 0; i < 4; i++)                     // A: 128 rows x 64 k
      GLL16(gA + (size_t)(i * 32) * 1024 + k0, As + (i * 256 + t) * 8);
#pragma unroll
    for (int i = 0; i < 2; i++)                     // B: 64 rows x 64 k
      GLL16(gB + (size_t)(i * 32) * 1024 + k0, Bs + (i * 256 + t) * 8);
    __syncthreads();
#pragma unroll
    for (int ks = 0; ks < 2; ks++) {
      short8 af[4], bf[2];
#pragma unroll
      for (int i = 0; i < 4; i++)
        af[i] = *(const short8*)(As + (wm + i * 16 + lid) * 64 + ks * 32 + quad * 8);
#pragma unroll
      for (int j = 0; j < 2; j++)
        bf[j] = *(const short8*)(Bs + (wn + j * 16 + lid) * 64 + ks * 32 + quad * 8);
#pragma unroll
      for (int i = 0; i < 4; i++)
#pragma unroll
        for (int j = 0; j < 2; j++)
          acc[i][j] = MFMA16(bf[j], af[i], acc[i][j]);   // swapped
    }
  }
#pragma unroll
  for (int jn = 0; jn < 2; jn++) {
    int nn = n0 + wn + jn * 16 + quad * 4;
    float4 b4 = *(const float4*)(Bi + nn);
#pragma unroll
    for (int im = 0; im < 4; im++) {
      int m = m0 + wm + im * 16 + lid;
      float4 ov;
      ov.x = acc[im][jn][0] + b4.x;
      ov.y = acc[im][jn][1] + b4.y;
      ov.z = acc[im][jn][2] + b4.z;
      ov.w = acc[im][jn][3] + b4.w;
      *(float4*)(O + (size_t)m * 1024 + nn) = ov;
    }
  }
}

// ---------------------------------------------------------------------------
// RoPE apply (reference variant), in-place on bf16 [B,H,S,64].
// ---------------------------------------------------------------------------
__global__ __launch_bounds__(256) void rope_kernel(unsigned short* __restrict__ Q,
                                                   unsigned short* __restrict__ Kp,
                                                   const float* __restrict__ tab)
{
  int row = blockIdx.x * 256 + threadIdx.x;
  unsigned short* P = ((blockIdx.y == 0) ? Q : Kp) + (size_t)row * 64;
  const float* tr = tab + (size_t)(row & 2047) * 64;

  short8 xv[8];
#pragma unroll
  for (int c = 0; c < 8; c++) xv[c] = *(const short8*)(P + c * 8);
#define XE(i) bf2f((unsigned short)xv[(i) >> 3][(i) & 7])
  short8 ov[8];
#pragma unroll
  for (int j = 0; j < 32; j++) {
    float cs = tr[j], sn = tr[32 + j];
    float yl = XE(j) * cs      - XE(2 * j + 1) * sn;
    float yh = XE(j + 32) * cs + XE(2 * j)     * sn;
    ov[j >> 3][j & 7]       = (short)f2bf(yl);
    ov[(j >> 3) + 4][j & 7] = (short)f2bf(yh);
  }
#undef XE
#pragma unroll
  for (int c = 0; c < 8; c++) *(short8*)(P + c * 8) = ov[c];
}

// ---------------------------------------------------------------------------
// Flash attention, 4 strips/block, k-split=2, XCD swizzle, (128,1) bounds.
// R11 post-mortem: 4-strip at (128,2) spilled ~40 regs (arch capped at 128:
// allocator splits the 256-total cap half arch/half acc) -> 216 MB scratch
// writes confounded the request-rate experiment. Fix: __launch_bounds__(128,1)
// lifts the cap to 512 total (arch ~256); natural usage ~170 arch + 64 acc
// = ~234 -> NO spill, and HW residency is still floor(512/234) = 2 waves/SIMD
// -> grid 1024 = 4 blocks/CU x 2 waves = same single full-residency pass.
// Request-rate theory (R9): each K/V tile feeds 4 strips (64 q-rows) ->
// half the global requests per unit work vs 2-strip.
// Tripwire: WRITE_SIZE must return to ~8.2 MB, FETCH to ~12.5 MB.
// ---------------------------------------------------------------------------
__global__ __launch_bounds__(128, 1) void attn_kernel(
    const unsigned short* __restrict__ Q, const unsigned short* __restrict__ Kg,
    const unsigned short* __restrict__ Vt, const float* __restrict__ relt,
    unsigned short* __restrict__ AO)
{
  __shared__ float Smem[5120];   // 20.5 KB: Ps (2x9216B) ∪ Cmb (20480B)

  const int tid  = threadIdx.x;
  const int wv   = tid >> 6;            // wave id 0/1
  const int lane = tid & 63;
  const int lid  = lane & 15;
  const int quad = lane >> 4;
  const int x    = blockIdx.x;          // 0..1023
  const int bh   = (x & 7) * 4 + (x >> 8);   // XCD-locality: same bh -> same xcd
  const int P    = (x >> 3) & 31;
  const int h    = bh & 15;

  // 4 strips: heavy pair (q0,q1) + light pair (q2,q3); per-pair sums constant.
  const int q0 = 2032 - 32 * P;
  const int q1 = 2016 - 32 * P;
  const int q2 = 32 * P;
  const int q3 = 32 * P + 16;
  const int kend0 = q0 + 16;            // loop bound (max of all strips)
  const int kend2 = q2 + 16, kend3 = q3 + 16;

  const unsigned short* Qb = Q  + (size_t)bh * (2048 * 64);
  const unsigned short* Kb = Kg + (size_t)bh * (2048 * 64);
  const unsigned short* Vb = Vt + (size_t)bh * (64 * 2048);
  const float* relh = relt + h * 4095 + 2047;
  unsigned short* AOb = AO + (size_t)(bh >> 4) * (2048 * 1024) + h * 64;

  unsigned short* Psw = (unsigned short*)Smem + wv * 4608;  // 64 rows x 72

  const int qbase[4] = {q0, q1, q2, q3};
  short8 aq[4][2];
#pragma unroll
  for (int s = 0; s < 4; s++) {
    const unsigned short* qp = Qb + (size_t)(qbase[s] + lid) * 64;
    aq[s][0] = *(const short8*)(qp + quad * 8);
    aq[s][1] = *(const short8*)(qp + 32 + quad * 8);
  }

  f32x4 acc[4][4];
  float l[4][4];
#pragma unroll
  for (int s = 0; s < 4; s++)
#pragma unroll
    for (int dj = 0; dj < 4; dj++) {
      acc[s][dj] = (f32x4){0.f, 0.f, 0.f, 0.f};
      l[s][dj] = 0.f;
    }

  const unsigned short* kr = Kb + (size_t)lid * 64 + quad * 8;
  const unsigned short* vr = Vb + (size_t)lid * 2048 + quad * 8;

  short8 ck[4][2], nk[4][2], cv[4][2];

  auto loadK = [&](short8 (&fk)[4][2], int k0) {
#pragma unroll
    for (int x2 = 0; x2 < 4; x2++) {
      const unsigned short* kp = kr + (size_t)(k0 + x2 * 16) * 64;
      fk[x2][0] = *(const short8*)kp;
      fk[x2][1] = *(const short8*)(kp + 32);
    }
  };
  auto loadV = [&](short8 (&fv)[4][2], int k0) {
#pragma unroll
    for (int x2 = 0; x2 < 4; x2++) {
      const unsigned short* vp = vr + (size_t)(x2 * 16) * 2048 + k0;
      fv[x2][0] = *(const short8*)vp;
      fv[x2][1] = *(const short8*)(vp + 32);
    }
  };
  auto proc = [&](const short8 (&a_q)[2], f32x4 (&acc_)[4], float (&l_)[4],
                  int qr0, int k0, const short8 (&fk)[4][2],
                  const short8 (&fv)[4][2], int pbase) {
    f32x4 s4[4];
#pragma unroll
    for (int jt = 0; jt < 4; jt++) {
      s4[jt] = (f32x4){0.f, 0.f, 0.f, 0.f};
      s4[jt] = MFMA16(a_q[0], fk[jt][0], s4[jt]);
      s4[jt] = MFMA16(a_q[1], fk[jt][1], s4[jt]);
    }
#pragma unroll
    for (int jt = 0; jt < 4; jt++) {
      int kb = k0 + jt * 16 + lid;
      const float* rp = relh + (qr0 - kb);
#pragma unroll
      for (int r = 0; r < 4; r++) {
        float sc = fmaf(s4[jt][r], 0.125f, rp[r]);
        float pv = (kb > qr0 + r) ? 0.f : __expf(sc);
        l_[r] += pv;
        Psw[(pbase + quad * 4 + r) * 72 + jt * 16 + lid] = f2bf(pv);
      }
    }
    short8 ap0 = *(const short8*)(Psw + (pbase + lid) * 72 + quad * 8);
    short8 ap1 = *(const short8*)(Psw + (pbase + lid) * 72 + 32 + quad * 8);
#pragma unroll
    for (int dj = 0; dj < 4; dj++) {
      acc_[dj] = MFMA16(ap0, fv[dj][0], acc_[dj]);
      acc_[dj] = MFMA16(ap1, fv[dj][1], acc_[dj]);
    }
  };

  const int qr0q = q0 + quad * 4, qr1q = q1 + quad * 4;
  const int qr2q = q2 + quad * 4, qr3q = q3 + quad * 4;

  auto PROCS = [&](int k0, const short8 (&fk)[4][2], const short8 (&fv)[4][2]) {
    proc(aq[0], acc[0], l[0], qr0q, k0, fk, fv, 0);
    proc(aq[1], acc[1], l[1], qr1q, k0, fk, fv, 16);
    if (k0 < kend2) proc(aq[2], acc[2], l[2], qr2q, k0, fk, fv, 32);
    if (k0 < kend3) proc(aq[3], acc[3], l[3], qr3q, k0, fk, fv, 48);
  };

  int k0 = wv * 64;               // interleaved k-split: parity of (k0/64)
  if (k0 < kend0) {
    loadK(ck, k0);
    while (true) {
      int k1 = k0 + 128;
      if (k1 < kend0) loadK(nk, k1);
      loadV(cv, k0);
      PROCS(k0, ck, cv);
      if (k1 >= kend0) break;
      k0 = k1; k1 = k0 + 128;
      if (k1 < kend0) loadK(ck, k1);
      loadV(cv, k0);
      PROCS(k0, nk, cv);
      if (k1 >= kend0) break;
      k0 = k1;
    }
  }

  // reduce l across the 16 lanes of each quad (within wave)
#pragma unroll
  for (int d2 = 1; d2 < 16; d2 <<= 1)
#pragma unroll
    for (int s = 0; s < 4; s++)
#pragma unroll
      for (int r = 0; r < 4; r++)
        l[s][r] += __shfl_xor(l[s][r], d2);

  // Ps is dead from here; Cmb aliases it -> barrier before overwrite.
  __syncthreads();
  if (wv == 1) {
    float* C = Smem + lane * 80;
#pragma unroll
    for (int s = 0; s < 4; s++) {
#pragma unroll
      for (int dj = 0; dj < 4; dj++)
#pragma unroll
        for (int r = 0; r < 4; r++)
          C[s * 20 + dj * 4 + r] = acc[s][dj][r];
#pragma unroll
      for (int r = 0; r < 4; r++)
        C[s * 20 + 16 + r] = l[s][r];
    }
  }
  __syncthreads();
  if (wv == 0) {
    const float* C = Smem + lane * 80;
#pragma unroll
    for (int s = 0; s < 4; s++) {
#pragma unroll
      for (int dj = 0; dj < 4; dj++)
#pragma unroll
        for (int r = 0; r < 4; r++)
          acc[s][dj][r] += C[s * 20 + dj * 4 + r];
#pragma unroll
      for (int r = 0; r < 4; r++)
        l[s][r] += C[s * 20 + 16 + r];
    }
    const int qrq[4] = {qr0q, qr1q, qr2q, qr3q};
#pragma unroll
    for (int s = 0; s < 4; s++)
#pragma unroll
      for (int r = 0; r < 4; r++) {
        float rl = 1.f / l[s][r];
#pragma unroll
        for (int dj = 0; dj < 4; dj++) {
          float vv = fminf(fmaxf(acc[s][dj][r] * rl, -30.f), 30.f);
          AOb[(size_t)(qrq[s] + r) * 1024 + dj * 16 + lid] = f2bf(vv);
        }
      }
  }
}

// ---------------------------------------------------------------------------
extern "C" void kernel_launch(void* const* d_in, const int* in_sizes, int n_in,
                              void* d_out, int out_size, void* d_ws, size_t ws_size,
                              hipStream_t stream) {
  const float* query  = (const float*)d_in[0];
  const float* key_in = (const float*)d_in[1];
  const float* value  = (const float*)d_in[2];
  const float* wq = (const float*)d_in[4];
  const float* bq = (const float*)d_in[5];
  const float* wk = (const float*)d_in[6];
  const float* bk = (const float*)d_in[7];
  const float* wv = (const float*)d_in[8];
  const float* bv = (const float*)d_in[9];
  const float* wo = (const float*)d_in[10];
  const float* bo = (const float*)d_in[11];
  const float* rel = (const float*)d_in[12];

  char* ws = (char*)d_ws;
  unsigned short* Xq = (unsigned short*)(ws);                 // 8.39 MB
  unsigned short* Xk = (unsigned short*)(ws + 8388608);
  unsigned short* Xv = (unsigned short*)(ws + 16777216);
  unsigned short* Wq = (unsigned short*)(ws + 25165824);      // Wq|Wk|Wv|Wo
  unsigned short* Wk = (unsigned short*)(ws + 27262976);      //  contiguous
  unsigned short* Wv = (unsigned short*)(ws + 29360128);      //  -> Wcat
  unsigned short* Wo = (unsigned short*)(ws + 31457280);
  unsigned short* Qr  = (unsigned short*)(ws + 33554432);     // 8.39 MB
  unsigned short* Kr  = (unsigned short*)(ws + 41943040);
  unsigned short* Vtr = (unsigned short*)(ws + 50331648);     // [B,H,D,S]
  unsigned short* AOp = Xq;            // alias: Xq dead after gemm_qkv
  // tab/relt live in d_out scratch (overwritten by gemm_out at the end)
  float* out  = (float*)d_out;
  float* tab  = out;                   // 131072 floats
  float* relt = out + 131072;          // 65520 floats

  dim3 blk(256);
  prep_kernel<<<dim3(8704), blk, 0, stream>>>(
      query, key_in, value, wq, wk, wv, wo,
      Xq, Xk, Xv, Wq, Wk, Wv, Wo, tab, relt, rel);
  gemm_qkv<<<dim3(24, 32), blk, 0, stream>>>(
      Xq, Xk, Xv, Wq /*=Wcat*/, bq, bk, bv, Qr, Kr, Vtr);
  rope_kernel<<<dim3(256, 2), blk, 0, stream>>>(Qr, Kr, tab);
  attn_kernel<<<dim3(1024), dim3(128), 0, stream>>>(Qr, Kr, Vtr, relt, AOp);
  gemm_out<<<dim3(16, 32), blk, 0, stream>>>(AOp, Wo, bo, out);
}